// Round 4
// baseline (445.515 us; speedup 1.0000x reference)
//
#include <hip/hip_runtime.h>
#include <hip/hip_bf16.h>

static constexpr int F1 = 256;   // input features
static constexpr int H1 = 64;    // hidden dim
static constexpr int C2 = 32;    // output classes
static constexpr int BSH = 6;    // bucket shift: 64 nodes per bucket

typedef __attribute__((ext_vector_type(8))) short short8;
typedef __attribute__((ext_vector_type(4))) float f32x4;

__device__ __forceinline__ unsigned short f2b(float f) {
  __hip_bfloat16 h = __float2bfloat16(f);
  unsigned short u;
  __builtin_memcpy(&u, &h, 2);
  return u;
}
__device__ __forceinline__ float b2f(unsigned short u) {
  return __uint_as_float(((unsigned)u) << 16);
}

// ---------------- edge-index access (robust to int32 or int64 storage) -----
__device__ __forceinline__ int ld_src(const int* __restrict__ ei, int E, int e, bool is64) {
  return is64 ? ei[2 * (size_t)e] : ei[e];
}
__device__ __forceinline__ int ld_dst(const int* __restrict__ ei, int E, int e, bool is64) {
  return is64 ? ei[2 * ((size_t)E + (size_t)e)] : ei[(size_t)E + (size_t)e];
}

__global__ __launch_bounds__(256) void k_detect(const int* __restrict__ ei, unsigned* __restrict__ flag) {
  __shared__ int nz;
  if (threadIdx.x == 0) nz = 0;
  __syncthreads();
  for (int i = threadIdx.x; i < 2048; i += 256) {
    if (ei[2 * i + 1] != 0) nz = 1;  // benign race
  }
  __syncthreads();
  if (threadIdx.x == 0) flag[0] = (nz == 0) ? 1u : 0u;  // 1 => int64 layout
}

// ---------------- bucket histogram (LDS-aggregated) --------------------------
__global__ __launch_bounds__(256) void k_bhist(const int* __restrict__ ei, int E,
                                               const unsigned* __restrict__ flag,
                                               unsigned* __restrict__ bcnt, int nb) {
  __shared__ unsigned h[1600];
  const bool is64 = flag[0] != 0;
  for (int i = threadIdx.x; i < nb; i += 256) h[i] = 0;
  __syncthreads();
  const int stride = gridDim.x * 256;
  for (int e = blockIdx.x * 256 + threadIdx.x; e < E; e += stride) {
    int d = ld_dst(ei, E, e, is64);
    atomicAdd(&h[d >> BSH], 1u);
  }
  __syncthreads();
  for (int i = threadIdx.x; i < nb; i += 256) {
    unsigned v = h[i];
    if (v) atomicAdd(&bcnt[i], v);
  }
}

// ---------------- exclusive scan (chunk = 1024/block) ------------------------
__global__ __launch_bounds__(256) void k_scan_part(const unsigned* __restrict__ a, int n,
                                                   unsigned* __restrict__ part) {
  __shared__ unsigned s[256];
  const int base = blockIdx.x * 1024;
  unsigned v = 0;
  for (int i = threadIdx.x; i < 1024; i += 256) {
    int g = base + i;
    v += (g < n) ? a[g] : 0u;
  }
  s[threadIdx.x] = v;
  __syncthreads();
  for (int o = 128; o > 0; o >>= 1) {
    if (threadIdx.x < o) s[threadIdx.x] += s[threadIdx.x + o];
    __syncthreads();
  }
  if (threadIdx.x == 0) part[blockIdx.x] = s[0];
}

__global__ __launch_bounds__(64) void k_scan_top(unsigned* __restrict__ part, int np) {
  if (threadIdx.x == 0) {
    unsigned acc = 0;
    for (int i = 0; i < np; ++i) {
      unsigned t = part[i];
      part[i] = acc;
      acc += t;
    }
  }
}

__global__ __launch_bounds__(256) void k_scan_down(const unsigned* __restrict__ a, int n,
                                                   const unsigned* __restrict__ part,
                                                   unsigned* __restrict__ out) {
  __shared__ unsigned ts[256];
  const int t = threadIdx.x;
  const int base = blockIdx.x * 1024 + t * 4;
  unsigned l0 = (base + 0 < n) ? a[base + 0] : 0u;
  unsigned l1 = (base + 1 < n) ? a[base + 1] : 0u;
  unsigned l2 = (base + 2 < n) ? a[base + 2] : 0u;
  unsigned l3 = (base + 3 < n) ? a[base + 3] : 0u;
  ts[t] = l0 + l1 + l2 + l3;
  __syncthreads();
  for (int o = 1; o < 256; o <<= 1) {
    unsigned v = ts[t];
    unsigned add = (t >= o) ? ts[t - o] : 0u;
    __syncthreads();
    ts[t] = v + add;
    __syncthreads();
  }
  unsigned prefix = ((t > 0) ? ts[t - 1] : 0u) + part[blockIdx.x];
  if (base + 0 < n) out[base + 0] = prefix;
  prefix += l0;
  if (base + 1 < n) out[base + 1] = prefix;
  prefix += l1;
  if (base + 2 < n) out[base + 2] = prefix;
  prefix += l2;
  if (base + 3 < n) out[base + 3] = prefix;
}

// ---------------- bucket fill: partition (s,d) pairs by bucket ---------------
__global__ __launch_bounds__(256) void k_bfill(const int* __restrict__ ei, int E,
                                               const unsigned* __restrict__ flag,
                                               const unsigned* __restrict__ bo,
                                               unsigned* __restrict__ bfil,
                                               uint2* __restrict__ bpairs) {
  const bool is64 = flag[0] != 0;
  int e = blockIdx.x * 256 + threadIdx.x;
  if (e < E) {
    int s = ld_src(ei, E, e, is64);
    int d = ld_dst(ei, E, e, is64);
    int b = d >> BSH;
    unsigned pos = bo[b] + atomicAdd(&bfil[b], 1u);
    bpairs[pos] = make_uint2((unsigned)s, (unsigned)d);
  }
}

// ---------------- per-bucket CSR finish: deg, dis, off, binning — all in LDS -
__global__ __launch_bounds__(256) void k_bucket_csr(const unsigned* __restrict__ bo,
                                                    const uint2* __restrict__ bpairs,
                                                    int nb, int n, int E,
                                                    unsigned* __restrict__ off,
                                                    float* __restrict__ dis,
                                                    int* __restrict__ srcbin) {
  __shared__ unsigned ldeg[64], loff[64];
  const int b = blockIdx.x;
  const int tid = threadIdx.x;
  const int node0 = b << BSH;
  const int nn = min(64, n - node0);
  const unsigned beg = bo[b];
  const unsigned end = (b + 1 < nb) ? bo[b + 1] : (unsigned)E;
  if (tid < 64) ldeg[tid] = 0;
  __syncthreads();
  for (unsigned p = beg + tid; p < end; p += 256) {
    atomicAdd(&ldeg[bpairs[p].y - node0], 1u);
  }
  __syncthreads();
  if (tid < 64) {
    unsigned v = ldeg[tid];
    unsigned s = v;  // inclusive scan over the wave
#pragma unroll
    for (int o = 1; o < 64; o <<= 1) {
      unsigned t = __shfl_up(s, o, 64);
      if (tid >= o) s += t;
    }
    loff[tid] = s - v;  // exclusive
    if (tid < nn) {
      off[node0 + tid] = beg + (s - v);
      dis[node0 + tid] = 1.0f / sqrtf((float)(v + 1u));  // + self-loop
    }
  }
  __syncthreads();
  if (tid < 64) ldeg[tid] = 0;  // reuse as fill counters
  __syncthreads();
  for (unsigned p = beg + tid; p < end; p += 256) {
    uint2 e = bpairs[p];
    unsigned li = e.y - node0;
    unsigned pos = loff[li] + atomicAdd(&ldeg[li], 1u);
    srcbin[beg + pos] = (int)e.x;
  }
}

// ---------------- GEMM1 (MFMA): xw1' = dis .* (x @ W1), bf16 out -------------
__global__ __launch_bounds__(256) void k_gemm1(const float* __restrict__ x,
                                               const float* __restrict__ W,
                                               const float* __restrict__ dis,
                                               unsigned short* __restrict__ y,
                                               int n, int ntiles) {
  __shared__ __align__(16) unsigned short wt[64][264];
  const int tid = threadIdx.x;
  for (int i = tid; i < F1 * 16; i += 256) {
    int k = i >> 4;
    int c = (i & 15) * 4;
    float4 v = reinterpret_cast<const float4*>(W)[i];
    wt[c + 0][k] = f2b(v.x);
    wt[c + 1][k] = f2b(v.y);
    wt[c + 2][k] = f2b(v.z);
    wt[c + 3][k] = f2b(v.w);
  }
  __syncthreads();

  const int wq = tid >> 6, l = tid & 63;
  const int lr = l & 15, lk = l >> 4;

  for (int t = blockIdx.x; t < ntiles; t += gridDim.x) {
    const int r0 = t * 128 + wq * 32;
    if (r0 >= n) continue;
    f32x4 acc[2][4] = {};
    const float* xr0 = x + (size_t)(r0 + lr) * F1;
    const float* xr1 = xr0 + (size_t)16 * F1;
#pragma unroll
    for (int kc = 0; kc < 8; ++kc) {
      const int kb = kc * 32 + lk * 8;
      float4 p0 = *reinterpret_cast<const float4*>(xr0 + kb);
      float4 p1 = *reinterpret_cast<const float4*>(xr0 + kb + 4);
      float4 q0 = *reinterpret_cast<const float4*>(xr1 + kb);
      float4 q1 = *reinterpret_cast<const float4*>(xr1 + kb + 4);
      short8 a0, a1;
      a0[0] = f2b(p0.x); a0[1] = f2b(p0.y); a0[2] = f2b(p0.z); a0[3] = f2b(p0.w);
      a0[4] = f2b(p1.x); a0[5] = f2b(p1.y); a0[6] = f2b(p1.z); a0[7] = f2b(p1.w);
      a1[0] = f2b(q0.x); a1[1] = f2b(q0.y); a1[2] = f2b(q0.z); a1[3] = f2b(q0.w);
      a1[4] = f2b(q1.x); a1[5] = f2b(q1.y); a1[6] = f2b(q1.z); a1[7] = f2b(q1.w);
#pragma unroll
      for (int nt = 0; nt < 4; ++nt) {
        short8 bb = *reinterpret_cast<const short8*>(&wt[nt * 16 + lr][kb]);
        acc[0][nt] = __builtin_amdgcn_mfma_f32_16x16x32_bf16(a0, bb, acc[0][nt], 0, 0, 0);
        acc[1][nt] = __builtin_amdgcn_mfma_f32_16x16x32_bf16(a1, bb, acc[1][nt], 0, 0, 0);
      }
    }
    float dsc0[4], dsc1[4];
#pragma unroll
    for (int r = 0; r < 4; ++r) {
      dsc0[r] = dis[r0 + lk * 4 + r];
      dsc1[r] = dis[r0 + 16 + lk * 4 + r];
    }
    unsigned short* yb = y + (size_t)r0 * H1;
#pragma unroll
    for (int nt = 0; nt < 4; ++nt)
#pragma unroll
      for (int r = 0; r < 4; ++r) {
        yb[(size_t)(lk * 4 + r) * H1 + nt * 16 + lr] = f2b(acc[0][nt][r] * dsc0[r]);
        yb[(size_t)(16 + lk * 4 + r) * H1 + nt * 16 + lr] = f2b(acc[1][nt][r] * dsc1[r]);
      }
  }
}

// ---------------- gather1: agg over CSR, fused relu(+b1), bf16 in/out --------
__global__ __launch_bounds__(256) void k_gather1(const unsigned* __restrict__ off, int n, int E,
                                                 const int* __restrict__ srcbin,
                                                 const float* __restrict__ dis,
                                                 const unsigned short* __restrict__ xw,
                                                 const float* __restrict__ b1,
                                                 unsigned short* __restrict__ h) {
  const int w = blockIdx.x * 4 + (threadIdx.x >> 6);
  const int lane = threadIdx.x & 63;
  if (w >= n) return;
  const float dd = dis[w];
  unsigned p = off[w];
  const unsigned end = (w + 1 < n) ? off[w + 1] : (unsigned)E;
  float acc = b2f(xw[(size_t)w * H1 + lane]);  // self-loop (pre-scaled)
  for (; p + 4 <= end; p += 4) {
    int s0 = srcbin[p + 0];
    int s1 = srcbin[p + 1];
    int s2 = srcbin[p + 2];
    int s3 = srcbin[p + 3];
    float v0 = b2f(xw[(size_t)s0 * H1 + lane]);
    float v1 = b2f(xw[(size_t)s1 * H1 + lane]);
    float v2 = b2f(xw[(size_t)s2 * H1 + lane]);
    float v3 = b2f(xw[(size_t)s3 * H1 + lane]);
    acc += v0 + v1 + v2 + v3;
  }
  for (; p < end; ++p) acc += b2f(xw[(size_t)srcbin[p] * H1 + lane]);
  h[(size_t)w * H1 + lane] = f2b(fmaxf(fmaf(acc, dd, b1[lane]), 0.0f));
}

// ---------------- GEMM2 (MFMA): xw2' = dis .* (h @ W2), bf16 in/out ----------
__global__ __launch_bounds__(256) void k_gemm2(const unsigned short* __restrict__ h,
                                               const float* __restrict__ W,
                                               const float* __restrict__ dis,
                                               unsigned short* __restrict__ y,
                                               int n, int ntiles) {
  __shared__ __align__(16) unsigned short wt[32][72];
  const int tid = threadIdx.x;
  for (int i = tid; i < H1 * 8; i += 256) {
    int k = i >> 3;
    int c = (i & 7) * 4;
    float4 v = reinterpret_cast<const float4*>(W)[i];
    wt[c + 0][k] = f2b(v.x);
    wt[c + 1][k] = f2b(v.y);
    wt[c + 2][k] = f2b(v.z);
    wt[c + 3][k] = f2b(v.w);
  }
  __syncthreads();

  const int wq = tid >> 6, l = tid & 63;
  const int lr = l & 15, lk = l >> 4;

  short8 bfrag[2][2];
#pragma unroll
  for (int kc = 0; kc < 2; ++kc)
#pragma unroll
    for (int nt = 0; nt < 2; ++nt)
      bfrag[kc][nt] = *reinterpret_cast<const short8*>(&wt[nt * 16 + lr][kc * 32 + lk * 8]);

  for (int t = blockIdx.x; t < ntiles; t += gridDim.x) {
    const int r0 = t * 128 + wq * 32;
    if (r0 >= n) continue;
    f32x4 acc[2][2] = {};
    const unsigned short* h0 = h + (size_t)(r0 + lr) * H1;
    const unsigned short* h1 = h0 + (size_t)16 * H1;
#pragma unroll
    for (int kc = 0; kc < 2; ++kc) {
      const int kb = kc * 32 + lk * 8;
      short8 a0 = *reinterpret_cast<const short8*>(h0 + kb);
      short8 a1 = *reinterpret_cast<const short8*>(h1 + kb);
#pragma unroll
      for (int nt = 0; nt < 2; ++nt) {
        acc[0][nt] = __builtin_amdgcn_mfma_f32_16x16x32_bf16(a0, bfrag[kc][nt], acc[0][nt], 0, 0, 0);
        acc[1][nt] = __builtin_amdgcn_mfma_f32_16x16x32_bf16(a1, bfrag[kc][nt], acc[1][nt], 0, 0, 0);
      }
    }
    float dsc0[4], dsc1[4];
#pragma unroll
    for (int r = 0; r < 4; ++r) {
      dsc0[r] = dis[r0 + lk * 4 + r];
      dsc1[r] = dis[r0 + 16 + lk * 4 + r];
    }
    unsigned short* yb = y + (size_t)r0 * C2;
#pragma unroll
    for (int nt = 0; nt < 2; ++nt)
#pragma unroll
      for (int r = 0; r < 4; ++r) {
        yb[(size_t)(lk * 4 + r) * C2 + nt * 16 + lr] = f2b(acc[0][nt][r] * dsc0[r]);
        yb[(size_t)(16 + lk * 4 + r) * C2 + nt * 16 + lr] = f2b(acc[1][nt][r] * dsc1[r]);
      }
  }
}

// ---------------- gather2: final aggregation, +b2, fp32 out ------------------
__global__ __launch_bounds__(256) void k_gather2(const unsigned* __restrict__ off, int n, int E,
                                                 const int* __restrict__ srcbin,
                                                 const float* __restrict__ dis,
                                                 const unsigned short* __restrict__ xw,
                                                 const float* __restrict__ b2,
                                                 float* __restrict__ out) {
  const int w = blockIdx.x * 4 + (threadIdx.x >> 6);
  const int lane = threadIdx.x & 63;
  const int c = lane & 31;
  const int hs = lane >> 5;  // 2 edge streams
  if (w >= n) return;
  const float dd = dis[w];
  const unsigned beg = off[w];
  const unsigned end = (w + 1 < n) ? off[w + 1] : (unsigned)E;
  float acc = (hs == 0) ? b2f(xw[(size_t)w * C2 + c]) : 0.0f;  // self-loop
  unsigned p = beg + hs;
  for (; p + 4 <= end; p += 4) {
    int s0 = srcbin[p];
    int s1 = srcbin[p + 2];
    acc += b2f(xw[(size_t)s0 * C2 + c]) + b2f(xw[(size_t)s1 * C2 + c]);
  }
  for (; p < end; p += 2) acc += b2f(xw[(size_t)srcbin[p] * C2 + c]);
  acc += __shfl_xor(acc, 32, 64);
  if (hs == 0) out[(size_t)w * C2 + c] = fmaf(acc, dd, b2[c]);
}

// ---------------- launch -----------------------------------------------------
extern "C" void kernel_launch(void* const* d_in, const int* in_sizes, int n_in,
                              void* d_out, int out_size, void* d_ws, size_t ws_size,
                              hipStream_t stream) {
  const float* x  = (const float*)d_in[0];
  const int*   ei = (const int*)d_in[1];
  const float* W1 = (const float*)d_in[2];
  const float* b1 = (const float*)d_in[3];
  const float* W2 = (const float*)d_in[4];
  const float* b2 = (const float*)d_in[5];
  float* out = (float*)d_out;

  const int n = in_sizes[0] / F1;  // 100000
  const int E = in_sizes[1] / 2;   // 1600000
  const int nb = (n + 63) >> BSH;  // 1563 buckets

  char* ws = (char*)d_ws;
  size_t woff = 0;
  auto take = [&](size_t bytes) -> void* {
    void* p = ws + woff;
    woff += (bytes + 255) & ~(size_t)255;
    return p;
  };
  float*    dis    = (float*)take((size_t)n * 4);
  unsigned* off    = (unsigned*)take((size_t)n * 4);
  unsigned* bcnt   = (unsigned*)take((size_t)nb * 4);
  unsigned* bo     = (unsigned*)take((size_t)nb * 4);
  unsigned* bfil   = (unsigned*)take((size_t)nb * 4);
  unsigned* part   = (unsigned*)take(1024);
  unsigned* flag   = (unsigned*)take(256);
  int*      srcbin = (int*)take((size_t)E * 4);
  // big region: bpairs (E*8) aliases xw1 (n*H1*2); bpairs dead before gemm1.
  char*     big    = (char*)take((size_t)E * 8 > (size_t)n * H1 * 2 ? (size_t)E * 8
                                                                     : (size_t)n * H1 * 2);
  uint2*          bpairs = (uint2*)big;
  unsigned short* xw1    = (unsigned short*)big;
  unsigned short* h      = (unsigned short*)take((size_t)n * H1 * 2);
  unsigned short* xw2    = (unsigned short*)take((size_t)n * C2 * 2);
  (void)ws_size;

  const int np = (nb + 1023) / 1024;   // bucket-scan chunks
  const int ntiles = (n + 127) / 128;

  hipMemsetAsync(bcnt, 0, (size_t)nb * 4, stream);
  hipMemsetAsync(bfil, 0, (size_t)nb * 4, stream);

  k_detect<<<1, 256, 0, stream>>>(ei, flag);
  k_bhist<<<512, 256, 0, stream>>>(ei, E, flag, bcnt, nb);
  k_scan_part<<<np, 256, 0, stream>>>(bcnt, nb, part);
  k_scan_top<<<1, 64, 0, stream>>>(part, np);
  k_scan_down<<<np, 256, 0, stream>>>(bcnt, nb, part, bo);
  k_bfill<<<(E + 255) / 256, 256, 0, stream>>>(ei, E, flag, bo, bfil, bpairs);
  k_bucket_csr<<<nb, 256, 0, stream>>>(bo, bpairs, nb, n, E, off, dis, srcbin);

  k_gemm1<<<512, 256, 0, stream>>>(x, W1, dis, xw1, n, ntiles);
  k_gather1<<<(n + 3) / 4, 256, 0, stream>>>(off, n, E, srcbin, dis, xw1, b1, h);

  k_gemm2<<<512, 256, 0, stream>>>(h, W2, dis, xw2, n, ntiles);
  k_gather2<<<(n + 3) / 4, 256, 0, stream>>>(off, n, E, srcbin, dis, xw2, b2, out);
}

// Round 5
// 249.617 us; speedup vs baseline: 1.7848x; 1.7848x over previous
//
#include <hip/hip_runtime.h>
#include <hip/hip_bf16.h>

static constexpr int F1 = 256;   // input features
static constexpr int H1 = 64;    // hidden dim
static constexpr int C2 = 32;    // output classes
static constexpr int BSH2 = 8;   // bucket shift: 256 nodes per bucket

typedef __attribute__((ext_vector_type(8))) short short8;
typedef __attribute__((ext_vector_type(4))) float f32x4;

__device__ __forceinline__ unsigned short f2b(float f) {
  __hip_bfloat16 h = __float2bfloat16(f);
  unsigned short u;
  __builtin_memcpy(&u, &h, 2);
  return u;
}
__device__ __forceinline__ float b2f(unsigned short u) {
  return __uint_as_float(((unsigned)u) << 16);
}

// ---------------- edge-index access (robust to int32 or int64 storage) -----
__device__ __forceinline__ int ld_src(const int* __restrict__ ei, int E, int e, bool is64) {
  return is64 ? ei[2 * (size_t)e] : ei[e];
}
__device__ __forceinline__ int ld_dst(const int* __restrict__ ei, int E, int e, bool is64) {
  return is64 ? ei[2 * ((size_t)E + (size_t)e)] : ei[(size_t)E + (size_t)e];
}

__global__ __launch_bounds__(256) void k_detect(const int* __restrict__ ei, unsigned* __restrict__ flag) {
  __shared__ int nz;
  if (threadIdx.x == 0) nz = 0;
  __syncthreads();
  for (int i = threadIdx.x; i < 2048; i += 256) {
    if (ei[2 * i + 1] != 0) nz = 1;  // benign race
  }
  __syncthreads();
  if (threadIdx.x == 0) flag[0] = (nz == 0) ? 1u : 0u;  // 1 => int64 layout
}

// ---------------- bucket histogram (LDS-aggregated) --------------------------
__global__ __launch_bounds__(256) void k_bhist(const int* __restrict__ ei, int E,
                                               const unsigned* __restrict__ flag,
                                               unsigned* __restrict__ bcnt, int nb) {
  __shared__ unsigned h[512];
  const bool is64 = flag[0] != 0;
  for (int i = threadIdx.x; i < nb; i += 256) h[i] = 0;
  __syncthreads();
  const int stride = gridDim.x * 256;
  for (int e = blockIdx.x * 256 + threadIdx.x; e < E; e += stride) {
    int d = ld_dst(ei, E, e, is64);
    atomicAdd(&h[d >> BSH2], 1u);
  }
  __syncthreads();
  for (int i = threadIdx.x; i < nb; i += 256) {
    unsigned v = h[i];
    if (v) atomicAdd(&bcnt[i], v);
  }
}

// ---------------- exclusive scan (chunk = 1024/block) ------------------------
__global__ __launch_bounds__(256) void k_scan_part(const unsigned* __restrict__ a, int n,
                                                   unsigned* __restrict__ part) {
  __shared__ unsigned s[256];
  const int base = blockIdx.x * 1024;
  unsigned v = 0;
  for (int i = threadIdx.x; i < 1024; i += 256) {
    int g = base + i;
    v += (g < n) ? a[g] : 0u;
  }
  s[threadIdx.x] = v;
  __syncthreads();
  for (int o = 128; o > 0; o >>= 1) {
    if (threadIdx.x < o) s[threadIdx.x] += s[threadIdx.x + o];
    __syncthreads();
  }
  if (threadIdx.x == 0) part[blockIdx.x] = s[0];
}

__global__ __launch_bounds__(64) void k_scan_top(unsigned* __restrict__ part, int np) {
  if (threadIdx.x == 0) {
    unsigned acc = 0;
    for (int i = 0; i < np; ++i) {
      unsigned t = part[i];
      part[i] = acc;
      acc += t;
    }
  }
}

__global__ __launch_bounds__(256) void k_scan_down(const unsigned* __restrict__ a, int n,
                                                   const unsigned* __restrict__ part,
                                                   unsigned* __restrict__ out) {
  __shared__ unsigned ts[256];
  const int t = threadIdx.x;
  const int base = blockIdx.x * 1024 + t * 4;
  unsigned l0 = (base + 0 < n) ? a[base + 0] : 0u;
  unsigned l1 = (base + 1 < n) ? a[base + 1] : 0u;
  unsigned l2 = (base + 2 < n) ? a[base + 2] : 0u;
  unsigned l3 = (base + 3 < n) ? a[base + 3] : 0u;
  ts[t] = l0 + l1 + l2 + l3;
  __syncthreads();
  for (int o = 1; o < 256; o <<= 1) {
    unsigned v = ts[t];
    unsigned add = (t >= o) ? ts[t - o] : 0u;
    __syncthreads();
    ts[t] = v + add;
    __syncthreads();
  }
  unsigned prefix = ((t > 0) ? ts[t - 1] : 0u) + part[blockIdx.x];
  if (base + 0 < n) out[base + 0] = prefix;
  prefix += l0;
  if (base + 1 < n) out[base + 1] = prefix;
  prefix += l1;
  if (base + 2 < n) out[base + 2] = prefix;
  prefix += l2;
  if (base + 3 < n) out[base + 3] = prefix;
}

// ---------------- partition: block-local 2-pass, range reservation ----------
// Each block: contiguous edge chunk -> LDS histogram -> ONE global atomic per
// (block,bucket) reserving a contiguous range -> re-read, LDS-bump, write.
__global__ __launch_bounds__(256) void k_part(const int* __restrict__ ei, int E,
                                              const unsigned* __restrict__ flag,
                                              const unsigned* __restrict__ bo,
                                              unsigned* __restrict__ bfil,
                                              uint2* __restrict__ bpairs,
                                              int nb, int chunk) {
  __shared__ unsigned lhist[512], gbase[512], lcnt[512];
  const bool is64 = flag[0] != 0;
  const int base = blockIdx.x * chunk;
  const int end = min(E, base + chunk);
  if (base >= E) return;
  for (int i = threadIdx.x; i < nb; i += 256) {
    lhist[i] = 0;
    lcnt[i] = 0;
  }
  __syncthreads();
  for (int e = base + threadIdx.x; e < end; e += 256) {
    int d = ld_dst(ei, E, e, is64);
    atomicAdd(&lhist[d >> BSH2], 1u);
  }
  __syncthreads();
  for (int i = threadIdx.x; i < nb; i += 256) {
    unsigned c = lhist[i];
    gbase[i] = c ? atomicAdd(&bfil[i], c) : 0u;
  }
  __syncthreads();
  for (int e = base + threadIdx.x; e < end; e += 256) {
    int s = ld_src(ei, E, e, is64);
    int d = ld_dst(ei, E, e, is64);
    int b = d >> BSH2;
    unsigned pos = gbase[b] + atomicAdd(&lcnt[b], 1u);
    bpairs[bo[b] + pos] = make_uint2((unsigned)s, (unsigned)d);
  }
}

// ---------------- per-bucket CSR finish: deg, dis, off, binning — all in LDS -
__global__ __launch_bounds__(256) void k_bucket_csr(const unsigned* __restrict__ bo,
                                                    const uint2* __restrict__ bpairs,
                                                    int nb, int n, int E,
                                                    unsigned* __restrict__ off,
                                                    float* __restrict__ dis,
                                                    int* __restrict__ srcbin) {
  __shared__ unsigned ldeg[256], loff[256], wsum[4];
  const int b = blockIdx.x;
  const int tid = threadIdx.x;
  const int node0 = b << BSH2;
  const int nn = min(256, n - node0);
  const unsigned beg = bo[b];
  const unsigned end = (b + 1 < nb) ? bo[b + 1] : (unsigned)E;

  ldeg[tid] = 0;
  __syncthreads();
  for (unsigned p = beg + tid; p < end; p += 256) {
    atomicAdd(&ldeg[bpairs[p].y - node0], 1u);
  }
  __syncthreads();
  unsigned v = ldeg[tid];
  unsigned s = v;  // inclusive scan: intra-wave shfl + cross-wave LDS
#pragma unroll
  for (int o = 1; o < 64; o <<= 1) {
    unsigned t = __shfl_up(s, o, 64);
    if ((tid & 63) >= o) s += t;
  }
  if ((tid & 63) == 63) wsum[tid >> 6] = s;
  __syncthreads();  // wsum visible; all ldeg reads done
  unsigned add = 0;
  for (int w = 0; w < (tid >> 6); ++w) add += wsum[w];
  s += add;
  loff[tid] = s - v;
  if (tid < nn) {
    off[node0 + tid] = beg + (s - v);
    dis[node0 + tid] = 1.0f / sqrtf((float)(v + 1u));  // + self-loop
  }
  ldeg[tid] = 0;  // reuse as fill counters (safe: all reads done pre-barrier)
  __syncthreads();
  for (unsigned p = beg + tid; p < end; p += 256) {
    uint2 e = bpairs[p];
    unsigned li = e.y - node0;
    unsigned pos = loff[li] + atomicAdd(&ldeg[li], 1u);
    srcbin[beg + pos] = (int)e.x;
  }
}

// ---------------- GEMM1 (MFMA): xw1' = dis .* (x @ W1), bf16 out -------------
__global__ __launch_bounds__(256) void k_gemm1(const float* __restrict__ x,
                                               const float* __restrict__ W,
                                               const float* __restrict__ dis,
                                               unsigned short* __restrict__ y,
                                               int n, int ntiles) {
  __shared__ __align__(16) unsigned short wt[64][264];
  const int tid = threadIdx.x;
  for (int i = tid; i < F1 * 16; i += 256) {
    int k = i >> 4;
    int c = (i & 15) * 4;
    float4 v = reinterpret_cast<const float4*>(W)[i];
    wt[c + 0][k] = f2b(v.x);
    wt[c + 1][k] = f2b(v.y);
    wt[c + 2][k] = f2b(v.z);
    wt[c + 3][k] = f2b(v.w);
  }
  __syncthreads();

  const int wq = tid >> 6, l = tid & 63;
  const int lr = l & 15, lk = l >> 4;

  for (int t = blockIdx.x; t < ntiles; t += gridDim.x) {
    const int r0 = t * 128 + wq * 32;
    if (r0 >= n) continue;
    f32x4 acc[2][4] = {};
    const float* xr0 = x + (size_t)(r0 + lr) * F1;
    const float* xr1 = xr0 + (size_t)16 * F1;
#pragma unroll
    for (int kc = 0; kc < 8; ++kc) {
      const int kb = kc * 32 + lk * 8;
      float4 p0 = *reinterpret_cast<const float4*>(xr0 + kb);
      float4 p1 = *reinterpret_cast<const float4*>(xr0 + kb + 4);
      float4 q0 = *reinterpret_cast<const float4*>(xr1 + kb);
      float4 q1 = *reinterpret_cast<const float4*>(xr1 + kb + 4);
      short8 a0, a1;
      a0[0] = f2b(p0.x); a0[1] = f2b(p0.y); a0[2] = f2b(p0.z); a0[3] = f2b(p0.w);
      a0[4] = f2b(p1.x); a0[5] = f2b(p1.y); a0[6] = f2b(p1.z); a0[7] = f2b(p1.w);
      a1[0] = f2b(q0.x); a1[1] = f2b(q0.y); a1[2] = f2b(q0.z); a1[3] = f2b(q0.w);
      a1[4] = f2b(q1.x); a1[5] = f2b(q1.y); a1[6] = f2b(q1.z); a1[7] = f2b(q1.w);
#pragma unroll
      for (int nt = 0; nt < 4; ++nt) {
        short8 bb = *reinterpret_cast<const short8*>(&wt[nt * 16 + lr][kb]);
        acc[0][nt] = __builtin_amdgcn_mfma_f32_16x16x32_bf16(a0, bb, acc[0][nt], 0, 0, 0);
        acc[1][nt] = __builtin_amdgcn_mfma_f32_16x16x32_bf16(a1, bb, acc[1][nt], 0, 0, 0);
      }
    }
    float dsc0[4], dsc1[4];
#pragma unroll
    for (int r = 0; r < 4; ++r) {
      dsc0[r] = dis[r0 + lk * 4 + r];
      dsc1[r] = dis[r0 + 16 + lk * 4 + r];
    }
    unsigned short* yb = y + (size_t)r0 * H1;
#pragma unroll
    for (int nt = 0; nt < 4; ++nt)
#pragma unroll
      for (int r = 0; r < 4; ++r) {
        yb[(size_t)(lk * 4 + r) * H1 + nt * 16 + lr] = f2b(acc[0][nt][r] * dsc0[r]);
        yb[(size_t)(16 + lk * 4 + r) * H1 + nt * 16 + lr] = f2b(acc[1][nt][r] * dsc1[r]);
      }
  }
}

// ---------------- gather1: agg over CSR, fused relu(+b1), bf16 in/out --------
__global__ __launch_bounds__(256) void k_gather1(const unsigned* __restrict__ off, int n, int E,
                                                 const int* __restrict__ srcbin,
                                                 const float* __restrict__ dis,
                                                 const unsigned short* __restrict__ xw,
                                                 const float* __restrict__ b1,
                                                 unsigned short* __restrict__ h) {
  const int w = blockIdx.x * 4 + (threadIdx.x >> 6);
  const int lane = threadIdx.x & 63;
  if (w >= n) return;
  const float dd = dis[w];
  unsigned p = off[w];
  const unsigned end = (w + 1 < n) ? off[w + 1] : (unsigned)E;
  float acc = b2f(xw[(size_t)w * H1 + lane]);  // self-loop (pre-scaled)
  for (; p + 4 <= end; p += 4) {
    int s0 = srcbin[p + 0];
    int s1 = srcbin[p + 1];
    int s2 = srcbin[p + 2];
    int s3 = srcbin[p + 3];
    float v0 = b2f(xw[(size_t)s0 * H1 + lane]);
    float v1 = b2f(xw[(size_t)s1 * H1 + lane]);
    float v2 = b2f(xw[(size_t)s2 * H1 + lane]);
    float v3 = b2f(xw[(size_t)s3 * H1 + lane]);
    acc += v0 + v1 + v2 + v3;
  }
  for (; p < end; ++p) acc += b2f(xw[(size_t)srcbin[p] * H1 + lane]);
  h[(size_t)w * H1 + lane] = f2b(fmaxf(fmaf(acc, dd, b1[lane]), 0.0f));
}

// ---------------- GEMM2 (MFMA): xw2' = dis .* (h @ W2), bf16 in/out ----------
__global__ __launch_bounds__(256) void k_gemm2(const unsigned short* __restrict__ h,
                                               const float* __restrict__ W,
                                               const float* __restrict__ dis,
                                               unsigned short* __restrict__ y,
                                               int n, int ntiles) {
  __shared__ __align__(16) unsigned short wt[32][72];
  const int tid = threadIdx.x;
  for (int i = tid; i < H1 * 8; i += 256) {
    int k = i >> 3;
    int c = (i & 7) * 4;
    float4 v = reinterpret_cast<const float4*>(W)[i];
    wt[c + 0][k] = f2b(v.x);
    wt[c + 1][k] = f2b(v.y);
    wt[c + 2][k] = f2b(v.z);
    wt[c + 3][k] = f2b(v.w);
  }
  __syncthreads();

  const int wq = tid >> 6, l = tid & 63;
  const int lr = l & 15, lk = l >> 4;

  short8 bfrag[2][2];
#pragma unroll
  for (int kc = 0; kc < 2; ++kc)
#pragma unroll
    for (int nt = 0; nt < 2; ++nt)
      bfrag[kc][nt] = *reinterpret_cast<const short8*>(&wt[nt * 16 + lr][kc * 32 + lk * 8]);

  for (int t = blockIdx.x; t < ntiles; t += gridDim.x) {
    const int r0 = t * 128 + wq * 32;
    if (r0 >= n) continue;
    f32x4 acc[2][2] = {};
    const unsigned short* h0 = h + (size_t)(r0 + lr) * H1;
    const unsigned short* h1 = h0 + (size_t)16 * H1;
#pragma unroll
    for (int kc = 0; kc < 2; ++kc) {
      const int kb = kc * 32 + lk * 8;
      short8 a0 = *reinterpret_cast<const short8*>(h0 + kb);
      short8 a1 = *reinterpret_cast<const short8*>(h1 + kb);
#pragma unroll
      for (int nt = 0; nt < 2; ++nt) {
        acc[0][nt] = __builtin_amdgcn_mfma_f32_16x16x32_bf16(a0, bfrag[kc][nt], acc[0][nt], 0, 0, 0);
        acc[1][nt] = __builtin_amdgcn_mfma_f32_16x16x32_bf16(a1, bfrag[kc][nt], acc[1][nt], 0, 0, 0);
      }
    }
    float dsc0[4], dsc1[4];
#pragma unroll
    for (int r = 0; r < 4; ++r) {
      dsc0[r] = dis[r0 + lk * 4 + r];
      dsc1[r] = dis[r0 + 16 + lk * 4 + r];
    }
    unsigned short* yb = y + (size_t)r0 * C2;
#pragma unroll
    for (int nt = 0; nt < 2; ++nt)
#pragma unroll
      for (int r = 0; r < 4; ++r) {
        yb[(size_t)(lk * 4 + r) * C2 + nt * 16 + lr] = f2b(acc[0][nt][r] * dsc0[r]);
        yb[(size_t)(16 + lk * 4 + r) * C2 + nt * 16 + lr] = f2b(acc[1][nt][r] * dsc1[r]);
      }
  }
}

// ---------------- gather2: final aggregation, +b2, fp32 out ------------------
__global__ __launch_bounds__(256) void k_gather2(const unsigned* __restrict__ off, int n, int E,
                                                 const int* __restrict__ srcbin,
                                                 const float* __restrict__ dis,
                                                 const unsigned short* __restrict__ xw,
                                                 const float* __restrict__ b2,
                                                 float* __restrict__ out) {
  const int w = blockIdx.x * 4 + (threadIdx.x >> 6);
  const int lane = threadIdx.x & 63;
  const int c = lane & 31;
  const int hs = lane >> 5;  // 2 edge streams
  if (w >= n) return;
  const float dd = dis[w];
  const unsigned beg = off[w];
  const unsigned end = (w + 1 < n) ? off[w + 1] : (unsigned)E;
  float acc = (hs == 0) ? b2f(xw[(size_t)w * C2 + c]) : 0.0f;  // self-loop
  unsigned p = beg + hs;
  for (; p + 4 <= end; p += 4) {
    int s0 = srcbin[p];
    int s1 = srcbin[p + 2];
    acc += b2f(xw[(size_t)s0 * C2 + c]) + b2f(xw[(size_t)s1 * C2 + c]);
  }
  for (; p < end; p += 2) acc += b2f(xw[(size_t)srcbin[p] * C2 + c]);
  acc += __shfl_xor(acc, 32, 64);
  if (hs == 0) out[(size_t)w * C2 + c] = fmaf(acc, dd, b2[c]);
}

// ---------------- launch -----------------------------------------------------
extern "C" void kernel_launch(void* const* d_in, const int* in_sizes, int n_in,
                              void* d_out, int out_size, void* d_ws, size_t ws_size,
                              hipStream_t stream) {
  const float* x  = (const float*)d_in[0];
  const int*   ei = (const int*)d_in[1];
  const float* W1 = (const float*)d_in[2];
  const float* b1 = (const float*)d_in[3];
  const float* W2 = (const float*)d_in[4];
  const float* b2 = (const float*)d_in[5];
  float* out = (float*)d_out;

  const int n = in_sizes[0] / F1;   // 100000
  const int E = in_sizes[1] / 2;    // 1600000
  const int nb = (n + 255) >> BSH2; // 391 buckets

  char* ws = (char*)d_ws;
  size_t woff = 0;
  auto take = [&](size_t bytes) -> void* {
    void* p = ws + woff;
    woff += (bytes + 255) & ~(size_t)255;
    return p;
  };
  float*    dis    = (float*)take((size_t)n * 4);
  unsigned* off    = (unsigned*)take((size_t)n * 4);
  unsigned* bcnt   = (unsigned*)take((size_t)nb * 4);
  unsigned* bo     = (unsigned*)take((size_t)nb * 4);
  unsigned* bfil   = (unsigned*)take((size_t)nb * 4);
  unsigned* part   = (unsigned*)take(1024);
  unsigned* flag   = (unsigned*)take(256);
  int*      srcbin = (int*)take((size_t)E * 4);
  // big region: bpairs (E*8) aliases xw1 (n*H1*2); bpairs dead before gemm1.
  char*     big    = (char*)take((size_t)E * 8 > (size_t)n * H1 * 2 ? (size_t)E * 8
                                                                     : (size_t)n * H1 * 2);
  uint2*          bpairs = (uint2*)big;
  unsigned short* xw1    = (unsigned short*)big;
  unsigned short* h      = (unsigned short*)take((size_t)n * H1 * 2);
  unsigned short* xw2    = (unsigned short*)take((size_t)n * C2 * 2);
  (void)ws_size;

  const int np = (nb + 1023) / 1024;
  const int ntiles = (n + 127) / 128;
  const int nblk = 128;  // partition blocks
  const int chunk = (((E + nblk - 1) / nblk) + 255) & ~255;

  hipMemsetAsync(bcnt, 0, (size_t)nb * 4, stream);
  hipMemsetAsync(bfil, 0, (size_t)nb * 4, stream);

  k_detect<<<1, 256, 0, stream>>>(ei, flag);
  k_bhist<<<256, 256, 0, stream>>>(ei, E, flag, bcnt, nb);
  k_scan_part<<<np, 256, 0, stream>>>(bcnt, nb, part);
  k_scan_top<<<1, 64, 0, stream>>>(part, np);
  k_scan_down<<<np, 256, 0, stream>>>(bcnt, nb, part, bo);
  k_part<<<nblk, 256, 0, stream>>>(ei, E, flag, bo, bfil, bpairs, nb, chunk);
  k_bucket_csr<<<nb, 256, 0, stream>>>(bo, bpairs, nb, n, E, off, dis, srcbin);

  k_gemm1<<<512, 256, 0, stream>>>(x, W1, dis, xw1, n, ntiles);
  k_gather1<<<(n + 3) / 4, 256, 0, stream>>>(off, n, E, srcbin, dis, xw1, b1, h);

  k_gemm2<<<512, 256, 0, stream>>>(h, W2, dis, xw2, n, ntiles);
  k_gather2<<<(n + 3) / 4, 256, 0, stream>>>(off, n, E, srcbin, dis, xw2, b2, out);
}

// Round 6
// 184.923 us; speedup vs baseline: 2.4092x; 1.3498x over previous
//
#include <hip/hip_runtime.h>
#include <hip/hip_bf16.h>

static constexpr int F1 = 256;   // input features
static constexpr int H1 = 64;    // hidden dim
static constexpr int C2 = 32;    // output classes
static constexpr int BSH2 = 8;   // bucket shift: 256 nodes per bucket
static constexpr int NBLK = 128; // partition blocks

typedef __attribute__((ext_vector_type(8))) short short8;
typedef __attribute__((ext_vector_type(4))) float f32x4;
typedef __attribute__((ext_vector_type(4))) unsigned short ushort4v;

__device__ __forceinline__ unsigned short f2b(float f) {
  __hip_bfloat16 h = __float2bfloat16(f);
  unsigned short u;
  __builtin_memcpy(&u, &h, 2);
  return u;
}
__device__ __forceinline__ float b2f(unsigned short u) {
  return __uint_as_float(((unsigned)u) << 16);
}

// ---------------- edge-index access (robust to int32 or int64 storage) -----
__device__ __forceinline__ int ld_src(const int* __restrict__ ei, int E, int e, bool is64) {
  return is64 ? ei[2 * (size_t)e] : ei[e];
}
__device__ __forceinline__ int ld_dst(const int* __restrict__ ei, int E, int e, bool is64) {
  return is64 ? ei[2 * ((size_t)E + (size_t)e)] : ei[(size_t)E + (size_t)e];
}

__global__ __launch_bounds__(256) void k_detect(const int* __restrict__ ei, unsigned* __restrict__ flag) {
  __shared__ int nz;
  if (threadIdx.x == 0) nz = 0;
  __syncthreads();
  for (int i = threadIdx.x; i < 2048; i += 256) {
    if (ei[2 * i + 1] != 0) nz = 1;  // benign race
  }
  __syncthreads();
  if (threadIdx.x == 0) flag[0] = (nz == 0) ? 1u : 0u;  // 1 => int64 layout
}

// ---------------- partition pass A: per-(block,bucket) histogram -------------
__global__ __launch_bounds__(256) void k_partA(const int* __restrict__ ei, int E,
                                               const unsigned* __restrict__ flag,
                                               unsigned* __restrict__ gcnt,
                                               int nb, int chunk) {
  __shared__ unsigned lhist[512];
  const bool is64 = flag[0] != 0;
  const int base = blockIdx.x * chunk;
  const int end = min(E, base + chunk);
  for (int i = threadIdx.x; i < nb; i += 256) lhist[i] = 0;
  __syncthreads();
  for (int e = base + threadIdx.x; e < end; e += 256) {
    int d = ld_dst(ei, E, e, is64);
    atomicAdd(&lhist[d >> BSH2], 1u);
  }
  __syncthreads();
  unsigned* g = gcnt + (size_t)blockIdx.x * nb;
  for (int i = threadIdx.x; i < nb; i += 256) g[i] = lhist[i];
}

// ---------------- per-bucket prefix over blocks (grid = nb, 128 thr) ---------
__global__ __launch_bounds__(128) void k_bscan(unsigned* __restrict__ gcnt,
                                               unsigned* __restrict__ bcnt, int nb) {
  __shared__ unsigned ws;
  const int b = blockIdx.x;
  const int t = threadIdx.x;  // block index 0..127
  unsigned v = gcnt[(size_t)t * nb + b];
  unsigned s = v;
#pragma unroll
  for (int o = 1; o < 64; o <<= 1) {
    unsigned u = __shfl_up(s, o, 64);
    if ((t & 63) >= o) s += u;
  }
  if (t == 63) ws = s;
  __syncthreads();
  if (t >= 64) s += ws;
  gcnt[(size_t)t * nb + b] = s - v;  // exclusive prefix (this block's base in bucket)
  if (t == 127) bcnt[b] = s;         // bucket total
}

// ---------------- single-block exclusive scan over buckets (nb <= 512) -------
__global__ __launch_bounds__(256) void k_scan_small(const unsigned* __restrict__ bcnt,
                                                    unsigned* __restrict__ bo, int nb) {
  __shared__ unsigned ts[256];
  const int t = threadIdx.x;
  unsigned l0 = (2 * t + 0 < nb) ? bcnt[2 * t + 0] : 0u;
  unsigned l1 = (2 * t + 1 < nb) ? bcnt[2 * t + 1] : 0u;
  ts[t] = l0 + l1;
  __syncthreads();
  for (int o = 1; o < 256; o <<= 1) {
    unsigned v = ts[t];
    unsigned add = (t >= o) ? ts[t - o] : 0u;
    __syncthreads();
    ts[t] = v + add;
    __syncthreads();
  }
  unsigned prefix = (t > 0) ? ts[t - 1] : 0u;
  if (2 * t + 0 < nb) bo[2 * t + 0] = prefix;
  if (2 * t + 1 < nb) bo[2 * t + 1] = prefix + l0;
}

// ---------------- partition pass B: write pairs into reserved ranges ---------
__global__ __launch_bounds__(256) void k_partB(const int* __restrict__ ei, int E,
                                               const unsigned* __restrict__ flag,
                                               const unsigned* __restrict__ bo,
                                               const unsigned* __restrict__ gcnt,
                                               uint2* __restrict__ bpairs,
                                               int nb, int chunk) {
  __shared__ unsigned gb[512];
  const bool is64 = flag[0] != 0;
  const int base = blockIdx.x * chunk;
  const int end = min(E, base + chunk);
  const unsigned* g = gcnt + (size_t)blockIdx.x * nb;
  for (int i = threadIdx.x; i < nb; i += 256) gb[i] = bo[i] + g[i];
  __syncthreads();
  for (int e = base + threadIdx.x; e < end; e += 256) {
    int s = ld_src(ei, E, e, is64);
    int d = ld_dst(ei, E, e, is64);
    unsigned pos = atomicAdd(&gb[d >> BSH2], 1u);
    bpairs[pos] = make_uint2((unsigned)s, (unsigned)d);
  }
}

// ---------------- per-bucket CSR finish: deg, dis, off, binning — all in LDS -
__global__ __launch_bounds__(256) void k_bucket_csr(const unsigned* __restrict__ bo,
                                                    const uint2* __restrict__ bpairs,
                                                    int nb, int n, int E,
                                                    unsigned* __restrict__ off,
                                                    float* __restrict__ dis,
                                                    int* __restrict__ srcbin) {
  __shared__ unsigned ldeg[256], loff[256], wsum[4];
  const int b = blockIdx.x;
  const int tid = threadIdx.x;
  const int node0 = b << BSH2;
  const int nn = min(256, n - node0);
  const unsigned beg = bo[b];
  const unsigned end = (b + 1 < nb) ? bo[b + 1] : (unsigned)E;

  ldeg[tid] = 0;
  __syncthreads();
  for (unsigned p = beg + tid; p < end; p += 256) {
    atomicAdd(&ldeg[bpairs[p].y - node0], 1u);
  }
  __syncthreads();
  unsigned v = ldeg[tid];
  unsigned s = v;  // inclusive scan: intra-wave shfl + cross-wave LDS
#pragma unroll
  for (int o = 1; o < 64; o <<= 1) {
    unsigned t = __shfl_up(s, o, 64);
    if ((tid & 63) >= o) s += t;
  }
  if ((tid & 63) == 63) wsum[tid >> 6] = s;
  __syncthreads();
  unsigned add = 0;
  for (int w = 0; w < (tid >> 6); ++w) add += wsum[w];
  s += add;
  loff[tid] = s - v;
  if (tid < nn) {
    off[node0 + tid] = beg + (s - v);
    dis[node0 + tid] = 1.0f / sqrtf((float)(v + 1u));  // + self-loop
  }
  ldeg[tid] = 0;  // reuse as fill counters
  __syncthreads();
  for (unsigned p = beg + tid; p < end; p += 256) {
    uint2 e = bpairs[p];
    unsigned li = e.y - node0;
    unsigned pos = loff[li] + atomicAdd(&ldeg[li], 1u);
    srcbin[beg + pos] = (int)e.x;
  }
}

// ---------------- GEMM1 (MFMA): xw1' = dis .* (x @ W1), bf16 out -------------
__global__ __launch_bounds__(256) void k_gemm1(const float* __restrict__ x,
                                               const float* __restrict__ W,
                                               const float* __restrict__ dis,
                                               unsigned short* __restrict__ y,
                                               int n, int ntiles) {
  __shared__ __align__(16) unsigned short wt[64][264];
  const int tid = threadIdx.x;
  for (int i = tid; i < F1 * 16; i += 256) {
    int k = i >> 4;
    int c = (i & 15) * 4;
    float4 v = reinterpret_cast<const float4*>(W)[i];
    wt[c + 0][k] = f2b(v.x);
    wt[c + 1][k] = f2b(v.y);
    wt[c + 2][k] = f2b(v.z);
    wt[c + 3][k] = f2b(v.w);
  }
  __syncthreads();

  const int wq = tid >> 6, l = tid & 63;
  const int lr = l & 15, lk = l >> 4;

  for (int t = blockIdx.x; t < ntiles; t += gridDim.x) {
    const int r0 = t * 128 + wq * 32;
    if (r0 >= n) continue;
    f32x4 acc[2][4] = {};
    const float* xr0 = x + (size_t)(r0 + lr) * F1;
    const float* xr1 = xr0 + (size_t)16 * F1;
#pragma unroll
    for (int kc = 0; kc < 8; ++kc) {
      const int kb = kc * 32 + lk * 8;
      float4 p0 = *reinterpret_cast<const float4*>(xr0 + kb);
      float4 p1 = *reinterpret_cast<const float4*>(xr0 + kb + 4);
      float4 q0 = *reinterpret_cast<const float4*>(xr1 + kb);
      float4 q1 = *reinterpret_cast<const float4*>(xr1 + kb + 4);
      short8 a0, a1;
      a0[0] = f2b(p0.x); a0[1] = f2b(p0.y); a0[2] = f2b(p0.z); a0[3] = f2b(p0.w);
      a0[4] = f2b(p1.x); a0[5] = f2b(p1.y); a0[6] = f2b(p1.z); a0[7] = f2b(p1.w);
      a1[0] = f2b(q0.x); a1[1] = f2b(q0.y); a1[2] = f2b(q0.z); a1[3] = f2b(q0.w);
      a1[4] = f2b(q1.x); a1[5] = f2b(q1.y); a1[6] = f2b(q1.z); a1[7] = f2b(q1.w);
#pragma unroll
      for (int nt = 0; nt < 4; ++nt) {
        short8 bb = *reinterpret_cast<const short8*>(&wt[nt * 16 + lr][kb]);
        acc[0][nt] = __builtin_amdgcn_mfma_f32_16x16x32_bf16(a0, bb, acc[0][nt], 0, 0, 0);
        acc[1][nt] = __builtin_amdgcn_mfma_f32_16x16x32_bf16(a1, bb, acc[1][nt], 0, 0, 0);
      }
    }
    float dsc0[4], dsc1[4];
#pragma unroll
    for (int r = 0; r < 4; ++r) {
      dsc0[r] = dis[r0 + lk * 4 + r];
      dsc1[r] = dis[r0 + 16 + lk * 4 + r];
    }
    unsigned short* yb = y + (size_t)r0 * H1;
#pragma unroll
    for (int nt = 0; nt < 4; ++nt)
#pragma unroll
      for (int r = 0; r < 4; ++r) {
        yb[(size_t)(lk * 4 + r) * H1 + nt * 16 + lr] = f2b(acc[0][nt][r] * dsc0[r]);
        yb[(size_t)(16 + lk * 4 + r) * H1 + nt * 16 + lr] = f2b(acc[1][nt][r] * dsc1[r]);
      }
  }
}

// ---------------- gather1: 4 edge-streams x 16 lanes x ushort4 ---------------
// h[d] = relu( dis[d] * sum_{s in bin(d) U {d}} xw1'[s] + b1 ), xw1' pre-scaled.
__global__ __launch_bounds__(256) void k_gather1(const unsigned* __restrict__ off, int n, int E,
                                                 const int* __restrict__ srcbin,
                                                 const float* __restrict__ dis,
                                                 const unsigned short* __restrict__ xw,
                                                 const float* __restrict__ b1,
                                                 unsigned short* __restrict__ h) {
  const int w = blockIdx.x * 4 + (threadIdx.x >> 6);
  if (w >= n) return;
  const int lane = threadIdx.x & 63;
  const int c4 = (lane & 15) * 4;  // column group
  const int st = lane >> 4;        // edge stream 0..3
  const float dd = dis[w];
  const unsigned beg = off[w];
  const unsigned end = (w + 1 < n) ? off[w + 1] : (unsigned)E;

  float a0 = 0.f, a1 = 0.f, a2 = 0.f, a3 = 0.f;
  float e0 = 0.f, e1 = 0.f, e2 = 0.f, e3 = 0.f;
  if (st == 0) {  // self-loop (pre-scaled)
    ushort4v u = *reinterpret_cast<const ushort4v*>(xw + (size_t)w * H1 + c4);
    a0 = b2f(u[0]); a1 = b2f(u[1]); a2 = b2f(u[2]); a3 = b2f(u[3]);
  }
  unsigned p = beg + st;
  for (; p + 4 < end; p += 8) {  // unroll x2 per stream
    int s0 = srcbin[p];
    int s1 = srcbin[p + 4];
    ushort4v u0 = *reinterpret_cast<const ushort4v*>(xw + (size_t)s0 * H1 + c4);
    ushort4v u1 = *reinterpret_cast<const ushort4v*>(xw + (size_t)s1 * H1 + c4);
    a0 += b2f(u0[0]); a1 += b2f(u0[1]); a2 += b2f(u0[2]); a3 += b2f(u0[3]);
    e0 += b2f(u1[0]); e1 += b2f(u1[1]); e2 += b2f(u1[2]); e3 += b2f(u1[3]);
  }
  if (p < end) {
    int s0 = srcbin[p];
    ushort4v u0 = *reinterpret_cast<const ushort4v*>(xw + (size_t)s0 * H1 + c4);
    a0 += b2f(u0[0]); a1 += b2f(u0[1]); a2 += b2f(u0[2]); a3 += b2f(u0[3]);
  }
  a0 += e0; a1 += e1; a2 += e2; a3 += e3;
  a0 += __shfl_xor(a0, 16, 64); a1 += __shfl_xor(a1, 16, 64);
  a2 += __shfl_xor(a2, 16, 64); a3 += __shfl_xor(a3, 16, 64);
  a0 += __shfl_xor(a0, 32, 64); a1 += __shfl_xor(a1, 32, 64);
  a2 += __shfl_xor(a2, 32, 64); a3 += __shfl_xor(a3, 32, 64);
  if (st == 0) {
    float4 bb = *reinterpret_cast<const float4*>(b1 + c4);
    ushort4v hv;
    hv[0] = f2b(fmaxf(fmaf(a0, dd, bb.x), 0.0f));
    hv[1] = f2b(fmaxf(fmaf(a1, dd, bb.y), 0.0f));
    hv[2] = f2b(fmaxf(fmaf(a2, dd, bb.z), 0.0f));
    hv[3] = f2b(fmaxf(fmaf(a3, dd, bb.w), 0.0f));
    *reinterpret_cast<ushort4v*>(h + (size_t)w * H1 + c4) = hv;
  }
}

// ---------------- GEMM2 (MFMA): xw2' = dis .* (h @ W2), bf16 in/out ----------
__global__ __launch_bounds__(256) void k_gemm2(const unsigned short* __restrict__ h,
                                               const float* __restrict__ W,
                                               const float* __restrict__ dis,
                                               unsigned short* __restrict__ y,
                                               int n, int ntiles) {
  __shared__ __align__(16) unsigned short wt[32][72];
  const int tid = threadIdx.x;
  for (int i = tid; i < H1 * 8; i += 256) {
    int k = i >> 3;
    int c = (i & 7) * 4;
    float4 v = reinterpret_cast<const float4*>(W)[i];
    wt[c + 0][k] = f2b(v.x);
    wt[c + 1][k] = f2b(v.y);
    wt[c + 2][k] = f2b(v.z);
    wt[c + 3][k] = f2b(v.w);
  }
  __syncthreads();

  const int wq = tid >> 6, l = tid & 63;
  const int lr = l & 15, lk = l >> 4;

  short8 bfrag[2][2];
#pragma unroll
  for (int kc = 0; kc < 2; ++kc)
#pragma unroll
    for (int nt = 0; nt < 2; ++nt)
      bfrag[kc][nt] = *reinterpret_cast<const short8*>(&wt[nt * 16 + lr][kc * 32 + lk * 8]);

  for (int t = blockIdx.x; t < ntiles; t += gridDim.x) {
    const int r0 = t * 128 + wq * 32;
    if (r0 >= n) continue;
    f32x4 acc[2][2] = {};
    const unsigned short* h0 = h + (size_t)(r0 + lr) * H1;
    const unsigned short* h1 = h0 + (size_t)16 * H1;
#pragma unroll
    for (int kc = 0; kc < 2; ++kc) {
      const int kb = kc * 32 + lk * 8;
      short8 a0 = *reinterpret_cast<const short8*>(h0 + kb);
      short8 a1 = *reinterpret_cast<const short8*>(h1 + kb);
#pragma unroll
      for (int nt = 0; nt < 2; ++nt) {
        acc[0][nt] = __builtin_amdgcn_mfma_f32_16x16x32_bf16(a0, bfrag[kc][nt], acc[0][nt], 0, 0, 0);
        acc[1][nt] = __builtin_amdgcn_mfma_f32_16x16x32_bf16(a1, bfrag[kc][nt], acc[1][nt], 0, 0, 0);
      }
    }
    float dsc0[4], dsc1[4];
#pragma unroll
    for (int r = 0; r < 4; ++r) {
      dsc0[r] = dis[r0 + lk * 4 + r];
      dsc1[r] = dis[r0 + 16 + lk * 4 + r];
    }
    unsigned short* yb = y + (size_t)r0 * C2;
#pragma unroll
    for (int nt = 0; nt < 2; ++nt)
#pragma unroll
      for (int r = 0; r < 4; ++r) {
        yb[(size_t)(lk * 4 + r) * C2 + nt * 16 + lr] = f2b(acc[0][nt][r] * dsc0[r]);
        yb[(size_t)(16 + lk * 4 + r) * C2 + nt * 16 + lr] = f2b(acc[1][nt][r] * dsc1[r]);
      }
  }
}

// ---------------- gather2: 8 edge-streams x 8 lanes x ushort4, fp32 out ------
__global__ __launch_bounds__(256) void k_gather2(const unsigned* __restrict__ off, int n, int E,
                                                 const int* __restrict__ srcbin,
                                                 const float* __restrict__ dis,
                                                 const unsigned short* __restrict__ xw,
                                                 const float* __restrict__ b2,
                                                 float* __restrict__ out) {
  const int w = blockIdx.x * 4 + (threadIdx.x >> 6);
  if (w >= n) return;
  const int lane = threadIdx.x & 63;
  const int c4 = (lane & 7) * 4;  // column group
  const int st = lane >> 3;       // edge stream 0..7
  const float dd = dis[w];
  const unsigned beg = off[w];
  const unsigned end = (w + 1 < n) ? off[w + 1] : (unsigned)E;

  float a0 = 0.f, a1 = 0.f, a2 = 0.f, a3 = 0.f;
  float e0 = 0.f, e1 = 0.f, e2 = 0.f, e3 = 0.f;
  if (st == 0) {  // self-loop (pre-scaled)
    ushort4v u = *reinterpret_cast<const ushort4v*>(xw + (size_t)w * C2 + c4);
    a0 = b2f(u[0]); a1 = b2f(u[1]); a2 = b2f(u[2]); a3 = b2f(u[3]);
  }
  unsigned p = beg + st;
  for (; p + 8 < end; p += 16) {  // unroll x2 per stream
    int s0 = srcbin[p];
    int s1 = srcbin[p + 8];
    ushort4v u0 = *reinterpret_cast<const ushort4v*>(xw + (size_t)s0 * C2 + c4);
    ushort4v u1 = *reinterpret_cast<const ushort4v*>(xw + (size_t)s1 * C2 + c4);
    a0 += b2f(u0[0]); a1 += b2f(u0[1]); a2 += b2f(u0[2]); a3 += b2f(u0[3]);
    e0 += b2f(u1[0]); e1 += b2f(u1[1]); e2 += b2f(u1[2]); e3 += b2f(u1[3]);
  }
  if (p < end) {
    int s0 = srcbin[p];
    ushort4v u0 = *reinterpret_cast<const ushort4v*>(xw + (size_t)s0 * C2 + c4);
    a0 += b2f(u0[0]); a1 += b2f(u0[1]); a2 += b2f(u0[2]); a3 += b2f(u0[3]);
  }
  a0 += e0; a1 += e1; a2 += e2; a3 += e3;
  a0 += __shfl_xor(a0, 8, 64);  a1 += __shfl_xor(a1, 8, 64);
  a2 += __shfl_xor(a2, 8, 64);  a3 += __shfl_xor(a3, 8, 64);
  a0 += __shfl_xor(a0, 16, 64); a1 += __shfl_xor(a1, 16, 64);
  a2 += __shfl_xor(a2, 16, 64); a3 += __shfl_xor(a3, 16, 64);
  a0 += __shfl_xor(a0, 32, 64); a1 += __shfl_xor(a1, 32, 64);
  a2 += __shfl_xor(a2, 32, 64); a3 += __shfl_xor(a3, 32, 64);
  if (st == 0) {
    float4 bb = *reinterpret_cast<const float4*>(b2 + c4);
    float4 o;
    o.x = fmaf(a0, dd, bb.x);
    o.y = fmaf(a1, dd, bb.y);
    o.z = fmaf(a2, dd, bb.z);
    o.w = fmaf(a3, dd, bb.w);
    *reinterpret_cast<float4*>(out + (size_t)w * C2 + c4) = o;
  }
}

// ---------------- launch -----------------------------------------------------
extern "C" void kernel_launch(void* const* d_in, const int* in_sizes, int n_in,
                              void* d_out, int out_size, void* d_ws, size_t ws_size,
                              hipStream_t stream) {
  const float* x  = (const float*)d_in[0];
  const int*   ei = (const int*)d_in[1];
  const float* W1 = (const float*)d_in[2];
  const float* b1 = (const float*)d_in[3];
  const float* W2 = (const float*)d_in[4];
  const float* b2 = (const float*)d_in[5];
  float* out = (float*)d_out;

  const int n = in_sizes[0] / F1;   // 100000
  const int E = in_sizes[1] / 2;    // 1600000
  const int nb = (n + 255) >> BSH2; // 391 buckets (<= 512)

  char* ws = (char*)d_ws;
  size_t woff = 0;
  auto take = [&](size_t bytes) -> void* {
    void* p = ws + woff;
    woff += (bytes + 255) & ~(size_t)255;
    return p;
  };
  float*    dis    = (float*)take((size_t)n * 4);
  unsigned* off    = (unsigned*)take((size_t)n * 4);
  unsigned* bcnt   = (unsigned*)take((size_t)nb * 4);
  unsigned* bo     = (unsigned*)take((size_t)nb * 4);
  unsigned* gcnt   = (unsigned*)take((size_t)NBLK * nb * 4);
  unsigned* flag   = (unsigned*)take(256);
  int*      srcbin = (int*)take((size_t)E * 4);
  // big region: bpairs (E*8) aliases xw1 (n*H1*2); bpairs dead before gemm1.
  char*     big    = (char*)take((size_t)E * 8 > (size_t)n * H1 * 2 ? (size_t)E * 8
                                                                     : (size_t)n * H1 * 2);
  uint2*          bpairs = (uint2*)big;
  unsigned short* xw1    = (unsigned short*)big;
  unsigned short* h      = (unsigned short*)take((size_t)n * H1 * 2);
  unsigned short* xw2    = (unsigned short*)take((size_t)n * C2 * 2);
  (void)ws_size;

  const int ntiles = (n + 127) / 128;
  const int chunk = (((E + NBLK - 1) / NBLK) + 255) & ~255;

  k_detect<<<1, 256, 0, stream>>>(ei, flag);
  k_partA<<<NBLK, 256, 0, stream>>>(ei, E, flag, gcnt, nb, chunk);
  k_bscan<<<nb, 128, 0, stream>>>(gcnt, bcnt, nb);
  k_scan_small<<<1, 256, 0, stream>>>(bcnt, bo, nb);
  k_partB<<<NBLK, 256, 0, stream>>>(ei, E, flag, bo, gcnt, bpairs, nb, chunk);
  k_bucket_csr<<<nb, 256, 0, stream>>>(bo, bpairs, nb, n, E, off, dis, srcbin);

  k_gemm1<<<512, 256, 0, stream>>>(x, W1, dis, xw1, n, ntiles);
  k_gather1<<<(n + 3) / 4, 256, 0, stream>>>(off, n, E, srcbin, dis, xw1, b1, h);

  k_gemm2<<<512, 256, 0, stream>>>(h, W2, dis, xw2, n, ntiles);
  k_gather2<<<(n + 3) / 4, 256, 0, stream>>>(off, n, E, srcbin, dis, xw2, b2, out);
}